// Round 4
// baseline (657.795 us; speedup 1.0000x reference)
//
#include <hip/hip_runtime.h>

#define N_NODESC 100000
#define N_EDGESC 1600000
#define IN_DIMC 128
#define HIDC 64
#define N_GRAPHSC 512
#define PAD_DEG 64

// ---------------- setup kernels ----------------

// zero 4 cnt replicas + compute per-graph bounds (independent work, one launch)
__global__ void zero_bounds_kernel(int* __restrict__ cntR, const int* __restrict__ batch,
                                   int* __restrict__ gstart) {
  int i = blockIdx.x * blockDim.x + threadIdx.x;
  if (i >= N_NODESC) return;
  cntR[i] = 0;
  cntR[N_NODESC + i] = 0;
  cntR[2 * N_NODESC + i] = 0;
  cntR[3 * N_NODESC + i] = 0;
  int b = batch[i];
  int prev = (i == 0) ? -1 : batch[i - 1];
  for (int g = prev + 1; g <= b; ++g) gstart[g] = i;
  if (i == N_NODESC - 1)
    for (int g = b + 1; g <= N_GRAPHSC; ++g) gstart[g] = N_NODESC;
}

// degree count into 4 replicas (cuts per-line RMW serialization 4x).
// KEEP SPLIT from fill: R1 measured fusing atomic+scattered-store into one
// kernel = 150us vs 65+50 split.
__global__ void deg_kernel(const int* __restrict__ dstv, int* __restrict__ cntR,
                           int* __restrict__ slot) {
  int e4 = (blockIdx.x * blockDim.x + threadIdx.x) * 4;
  if (e4 >= N_EDGESC) return;
  int4 d = *(const int4*)(dstv + e4);
  int4 s;
  s.x = atomicAdd(&cntR[d.x], 1);
  s.y = atomicAdd(&cntR[N_NODESC + d.y], 1);
  s.z = atomicAdd(&cntR[2 * N_NODESC + d.z], 1);
  s.w = atomicAdd(&cntR[3 * N_NODESC + d.w], 1);
  *(int4*)(slot + e4) = s;
}

// per-node: exclusive prefix over replicas -> offR, total cnt, dinv
__global__ void off_dinv_kernel(const int* __restrict__ cntR, int* __restrict__ offR,
                                int* __restrict__ cnt, float* __restrict__ dinv) {
  int i = blockIdx.x * blockDim.x + threadIdx.x;
  if (i >= N_NODESC) return;
  int c0 = cntR[i];
  int c1 = cntR[N_NODESC + i];
  int c2 = cntR[2 * N_NODESC + i];
  int c3 = cntR[3 * N_NODESC + i];
  offR[i] = c0;
  offR[N_NODESC + i] = c0 + c1;
  offR[2 * N_NODESC + i] = c0 + c1 + c2;
  int tot = c0 + c1 + c2 + c3;
  cnt[i] = tot;
  dinv[i] = rsqrtf((float)tot + 1.0f);
}

// atomic-free padded placement: csr_pad[d*64 + offR[r][d] + slot_r[e]] = src
__global__ void fill_pad_kernel(const int* __restrict__ srcv, const int* __restrict__ dstv,
                                const int* __restrict__ slot, const int* __restrict__ offR,
                                int* __restrict__ csr_pad) {
  int e4 = (blockIdx.x * blockDim.x + threadIdx.x) * 4;
  if (e4 >= N_EDGESC) return;
  int4 s = *(const int4*)(srcv + e4);
  int4 d = *(const int4*)(dstv + e4);
  int4 sl = *(const int4*)(slot + e4);
  int p0 = sl.x;
  int p1 = offR[d.y] + sl.y;
  int p2 = offR[N_NODESC + d.z] + sl.z;
  int p3 = offR[2 * N_NODESC + d.w] + sl.w;
  if (p0 < PAD_DEG) __builtin_nontemporal_store(s.x, &csr_pad[d.x * PAD_DEG + p0]);
  if (p1 < PAD_DEG) __builtin_nontemporal_store(s.y, &csr_pad[d.y * PAD_DEG + p1]);
  if (p2 < PAD_DEG) __builtin_nontemporal_store(s.z, &csr_pad[d.z * PAD_DEG + p2]);
  if (p3 < PAD_DEG) __builtin_nontemporal_store(s.w, &csr_pad[d.w * PAD_DEG + p3]);
}

// ---------------- GCN layer GEMM ----------------
// T[tile] = (X[tile] @ W) * dinv.  SINGLE-WAVE blocks: 64 threads, tile
// 128 rows x 64 cols, per-thread 8 rows x 16 cols.
//
// Design rationale (R2/R3 post-mortems):
//  - 782 blocks ~ 3/CU: no 2-block-serial CU tail (R3: 391 blocks = 2x span).
//  - single wave => NO barriers at all (DS ops are in-order per wave);
//    stage->compute phase flips cost nothing.
//  - global loads for chunk t+1 issued BEFORE compute of chunk t: ~4096
//    SIMD-cyc of FMA hides ~600-900 cyc HBM/L2 latency.  LDS double buffer
//    removes the write-after-read serialization.
//  - steady state per wave-k: 128 v_fmac (256 SIMD-cyc on one SIMD) vs
//    6 ds_read_b128; xs reads are 4-lane-broadcast (16 distinct addrs over
//    8 bank-quad classes x 2 via px swizzle) -> LDS far from binding.
#define GW_KC 16
#define GW_ST 144   // xs stride (floats); k-term 144 = 16 mod 32 collapses, px spreads banks
#define GW_WST 68   // ws stride; 68 = 4 mod 32 spreads the 16 k-rows across banks
#define GW_BLOCKS ((N_NODESC + 127) / 128)  // 782

template <int KT>
__global__ void __launch_bounds__(64)
gemm_wave_kernel(const float* __restrict__ X, const float* __restrict__ W,
                 const float* __restrict__ dinv, float* __restrict__ T) {
  __shared__ float xs[2][GW_KC * GW_ST];
  __shared__ float ws[2][GW_KC * GW_WST];
  int l = threadIdx.x;
  int rg = l >> 2;           // 0..15 -> rows rg*8..+7
  int cg = l & 3;            // 0..3  -> cols cg*16..+15
  int r0 = rg * 8;
  int c0 = cg * 16;
  int kq = cg * 4;           // k-quad this lane stages for xs
  int px = r0 + 4 * (r0 >> 5);  // swizzled physical col (max 132+7 < 144)
  int base = blockIdx.x * 128;

  float4 acc[8][4];
#pragma unroll
  for (int i = 0; i < 8; ++i)
#pragma unroll
    for (int j = 0; j < 4; ++j) acc[i][j] = make_float4(0.f, 0.f, 0.f, 0.f);

  float4 xv[8];
  float4 wv[4];

  // --- global load of chunk at k-base kb into regs (issued early) ---
  auto gload = [&](int kb) {
#pragma unroll
    for (int i = 0; i < 8; ++i) {
      int row = base + r0 + i;
      if (row >= N_NODESC) row = N_NODESC - 1;
      xv[i] = *(const float4*)(X + (size_t)row * KT + kb + kq);
    }
    // lane l covers W row kb+rg, cols c0..c0+15 (lanes -> 256B contiguous)
#pragma unroll
    for (int j = 0; j < 4; ++j)
      wv[j] = *(const float4*)(W + (size_t)(kb + rg) * HIDC + c0 + 4 * j);
  };

  // --- write staged regs into LDS buffer b (transpose xs) ---
  auto sstore = [&](int b) {
    const float* a = (const float*)xv;
#pragma unroll
    for (int c = 0; c < 4; ++c) {
      float4 lo = make_float4(a[0 * 4 + c], a[1 * 4 + c], a[2 * 4 + c], a[3 * 4 + c]);
      float4 hi = make_float4(a[4 * 4 + c], a[5 * 4 + c], a[6 * 4 + c], a[7 * 4 + c]);
      *(float4*)(&xs[b][(kq + c) * GW_ST + px]) = lo;
      *(float4*)(&xs[b][(kq + c) * GW_ST + px + 4]) = hi;
    }
#pragma unroll
    for (int j = 0; j < 4; ++j)
      *(float4*)(&ws[b][rg * GW_WST + c0 + 4 * j]) = wv[j];
  };

  gload(0);
  sstore(0);
  constexpr int NB = KT / GW_KC;
  for (int t = 0; t < NB; ++t) {
    int b = t & 1;
    if (t + 1 < NB) gload((t + 1) * GW_KC);  // in flight during compute
#pragma unroll
    for (int k = 0; k < GW_KC; ++k) {
      float4 xa = *(const float4*)(&xs[b][k * GW_ST + px]);
      float4 xb = *(const float4*)(&xs[b][k * GW_ST + px + 4]);
      float4 wq[4];
#pragma unroll
      for (int j = 0; j < 4; ++j) wq[j] = *(const float4*)(&ws[b][k * GW_WST + c0 + 4 * j]);
      float xf[8] = {xa.x, xa.y, xa.z, xa.w, xb.x, xb.y, xb.z, xb.w};
#pragma unroll
      for (int i = 0; i < 8; ++i)
#pragma unroll
        for (int j = 0; j < 4; ++j) {
          acc[i][j].x = fmaf(xf[i], wq[j].x, acc[i][j].x);
          acc[i][j].y = fmaf(xf[i], wq[j].y, acc[i][j].y);
          acc[i][j].z = fmaf(xf[i], wq[j].z, acc[i][j].z);
          acc[i][j].w = fmaf(xf[i], wq[j].w, acc[i][j].w);
        }
    }
    if (t + 1 < NB) sstore((t + 1) & 1);
  }

  // ---- epilogue: x dinv, store 8 rows x 16 cols ----
#pragma unroll
  for (int i = 0; i < 8; ++i) {
    int row = base + r0 + i;
    if (row < N_NODESC) {
      float dv = dinv[row];
#pragma unroll
      for (int j = 0; j < 4; ++j) {
        float4 o;
        o.x = acc[i][j].x * dv;
        o.y = acc[i][j].y * dv;
        o.z = acc[i][j].z * dv;
        o.w = acc[i][j].w * dv;
        *(float4*)(T + (size_t)row * HIDC + c0 + 4 * j) = o;
      }
    }
  }
}

// h[i][:] = relu(dinv[i]*(ts[i][:] + sum_{s in pad-row i} ts[s][:]) + b)
// Wave layout: lane l = (quarter q=l>>4, col-quad c=l&15). One float4 LOAD
// INSTRUCTION fetches 4 source rows (16B/lane, 1KB/instr). Quarter partials
// folded with shfl_xor(16/32) once per node.
__global__ void gather_kernel(const float* __restrict__ ts, const float* __restrict__ dinv,
                              const int* __restrict__ cnt, const int* __restrict__ csr_pad,
                              const float* __restrict__ bias, float* __restrict__ h) {
  int lane = threadIdx.x & 63;
  int node = (blockIdx.x * blockDim.x + threadIdx.x) >> 6;
  if (node >= N_NODESC) return;
  int q = lane >> 4;        // quarter: which of 4 concurrent edges
  int c = lane & 15;        // col-quad: features 4c..4c+3
  int deg = min(cnt[node], PAD_DEG);
  const int* __restrict__ row = csr_pad + node * PAD_DEG;
  const float4* __restrict__ ts4 = (const float4*)ts;
  float4 acc = make_float4(0.f, 0.f, 0.f, 0.f);
  int e = 0;
  // 16 edges per block: 4 idx loads + 4 float4 loads (16KB in flight across unroll)
  for (; e + 16 <= deg; e += 16) {
    int s0 = row[e + q];
    int s1 = row[e + 4 + q];
    int s2 = row[e + 8 + q];
    int s3 = row[e + 12 + q];
    float4 v0 = ts4[s0 * 16 + c];
    float4 v1 = ts4[s1 * 16 + c];
    float4 v2 = ts4[s2 * 16 + c];
    float4 v3 = ts4[s3 * 16 + c];
    acc.x += (v0.x + v1.x) + (v2.x + v3.x);
    acc.y += (v0.y + v1.y) + (v2.y + v3.y);
    acc.z += (v0.z + v1.z) + (v2.z + v3.z);
    acc.w += (v0.w + v1.w) + (v2.w + v3.w);
  }
  for (; e + 4 <= deg; e += 4) {
    int s0 = row[e + q];
    float4 v = ts4[s0 * 16 + c];
    acc.x += v.x;
    acc.y += v.y;
    acc.z += v.z;
    acc.w += v.w;
  }
  if (e < deg && q < deg - e) {  // tail 1..3 edges, quarters 0..r-1 active
    int s0 = row[e + q];
    float4 v = ts4[s0 * 16 + c];
    acc.x += v.x;
    acc.y += v.y;
    acc.z += v.z;
    acc.w += v.w;
  }
  // fold quarters: lanes ^16 then ^32
  acc.x += __shfl_xor(acc.x, 16);
  acc.y += __shfl_xor(acc.y, 16);
  acc.z += __shfl_xor(acc.z, 16);
  acc.w += __shfl_xor(acc.w, 16);
  acc.x += __shfl_xor(acc.x, 32);
  acc.y += __shfl_xor(acc.y, 32);
  acc.z += __shfl_xor(acc.z, 32);
  acc.w += __shfl_xor(acc.w, 32);
  if (q == 0) {
    float4 self = ts4[node * 16 + c];
    float4 bv = ((const float4*)bias)[c];
    float dv = dinv[node];
    float4 o;
    o.x = fmaxf(fmaf(acc.x + self.x, dv, bv.x), 0.f);
    o.y = fmaxf(fmaf(acc.y + self.y, dv, bv.y), 0.f);
    o.z = fmaxf(fmaf(acc.z + self.z, dv, bv.z), 0.f);
    o.w = fmaxf(fmaf(acc.w + self.w, dv, bv.w), 0.f);
    ((float4*)h)[node * 16 + c] = o;
  }
}

// ---------------- fused readout: score + softmax + weighted max-pool + MLP ----------------
__global__ void __launch_bounds__(256)
readout_kernel(const float* __restrict__ h, const float* __restrict__ closeness,
               const float* __restrict__ Wc, const float* __restrict__ bc,
               const int* __restrict__ gstart, const float* __restrict__ Wa1,
               const float* __restrict__ ba1, const float* __restrict__ Wa2,
               const float* __restrict__ ba2, float* __restrict__ out) {
  __shared__ float sArr[1024];
  __shared__ float red[256];
  __shared__ float cross[4 * 64];
  int g = blockIdx.x;
  int t = threadIdx.x;
  int n0 = gstart[g], n1 = gstart[g + 1];
  int count = n1 - n0;
  int cap = min(count, 1024);
  float wc0 = Wc[0], wc1 = Wc[1], wc2 = Wc[2], wc3 = Wc[3], wc4 = Wc[4], bcv = bc[0];
  float lmax = -3.4e38f;
  for (int idx = t; idx < cap; idx += 256) {
    const float* c = closeness + (size_t)(n0 + idx) * 5;
    float s = fmaf(c[4], wc4, fmaf(c[3], wc3, fmaf(c[2], wc2, fmaf(c[1], wc1, fmaf(c[0], wc0, bcv)))));
    sArr[idx] = s;
    lmax = fmaxf(lmax, s);
  }
  red[t] = lmax;
  __syncthreads();
  for (int s = 128; s > 0; s >>= 1) {
    if (t < s) red[t] = fmaxf(red[t], red[t + s]);
    __syncthreads();
  }
  float m = red[0];
  __syncthreads();
  float lsum = 0.f;
  for (int idx = t; idx < cap; idx += 256) {
    float e = expf(sArr[idx] - m);
    sArr[idx] = e;
    lsum += e;
  }
  red[t] = lsum;
  __syncthreads();
  for (int s = 128; s > 0; s >>= 1) {
    if (t < s) red[t] += red[t + s];
    __syncthreads();
  }
  float scale = (count > 0) ? ((float)count / red[0]) : 0.f;
  __syncthreads();
  int wv = t >> 6, lane = t & 63;
  float pmax = 0.f;  // values nonneg (relu * positive weight)
  for (int idx = wv; idx < cap; idx += 4) {
    float w = sArr[idx] * scale;
    pmax = fmaxf(pmax, w * h[(size_t)(n0 + idx) * HIDC + lane]);
  }
  cross[wv * 64 + lane] = pmax;
  __syncthreads();
  if (wv == 0) {
    float p = fmaxf(fmaxf(cross[lane], cross[64 + lane]),
                    fmaxf(cross[128 + lane], cross[192 + lane]));
    float o = 0.f;
#pragma unroll
    for (int tt = 0; tt < 16; ++tt) {
      float prod = p * Wa1[lane * 16 + tt];
#pragma unroll
      for (int off = 32; off > 0; off >>= 1) prod += __shfl_xor(prod, off);
      float a = fmaxf(prod + ba1[tt], 0.f);
      o += a * Wa2[tt];
    }
    if (lane == 0) out[g] = o + ba2[0];
  }
}

// ---------------- launch ----------------

extern "C" void kernel_launch(void* const* d_in, const int* in_sizes, int n_in,
                              void* d_out, int out_size, void* d_ws, size_t ws_size,
                              hipStream_t stream) {
  const float* x = (const float*)d_in[0];
  const int* ei = (const int*)d_in[1];
  const float* closeness = (const float*)d_in[2];
  const int* batch = (const int*)d_in[3];
  const float* W1 = (const float*)d_in[5];
  const float* b1 = (const float*)d_in[6];
  const float* W2 = (const float*)d_in[7];
  const float* b2 = (const float*)d_in[8];
  const float* W3 = (const float*)d_in[9];
  const float* b3 = (const float*)d_in[10];
  const float* Wc = (const float*)d_in[11];
  const float* bc = (const float*)d_in[12];
  const float* Wa1 = (const float*)d_in[13];
  const float* ba1 = (const float*)d_in[14];
  const float* Wa2 = (const float*)d_in[15];
  const float* ba2 = (const float*)d_in[16];
  float* out = (float*)d_out;
  const int* srcv = ei;
  const int* dstv = ei + N_EDGESC;

  char* ws = (char*)d_ws;
  size_t off = 0;
  auto alloc = [&](size_t bytes) -> void* {
    void* p = ws + off;
    off = (off + bytes + 255) & ~(size_t)255;
    return p;
  };
  float* tbuf = (float*)alloc(sizeof(float) * N_NODESC * HIDC);   // 25.6 MB
  float* hbuf = (float*)alloc(sizeof(float) * N_NODESC * HIDC);   // 25.6 MB
  int* csr_pad = (int*)alloc(sizeof(int) * N_NODESC * PAD_DEG);   // 25.6 MB
  int* slot = (int*)alloc(sizeof(int) * N_EDGESC);                // 6.4 MB
  int* cntR = (int*)alloc(sizeof(int) * N_NODESC * 4);            // 1.6 MB
  int* offR = (int*)alloc(sizeof(int) * N_NODESC * 3);            // 1.2 MB
  int* cnt = (int*)alloc(sizeof(int) * N_NODESC);
  float* dinv = (float*)alloc(sizeof(float) * N_NODESC);
  int* gstart = (int*)alloc(sizeof(int) * (N_GRAPHSC + 1));

  const int B = 256;
  int gN = (N_NODESC + B - 1) / B;           // 391
  int gE4 = (N_EDGESC / 4 + B - 1) / B;      // 1563
  int gGather = (N_NODESC * 64) / B;         // 25000

  zero_bounds_kernel<<<gN, B, 0, stream>>>(cntR, batch, gstart);
  deg_kernel<<<gE4, B, 0, stream>>>(dstv, cntR, slot);
  off_dinv_kernel<<<gN, B, 0, stream>>>(cntR, offR, cnt, dinv);
  fill_pad_kernel<<<gE4, B, 0, stream>>>(srcv, dstv, slot, offR, csr_pad);

  // layer 1 (K=128)
  gemm_wave_kernel<IN_DIMC><<<GW_BLOCKS, 64, 0, stream>>>(x, W1, dinv, tbuf);
  gather_kernel<<<gGather, B, 0, stream>>>(tbuf, dinv, cnt, csr_pad, b1, hbuf);
  // layer 2
  gemm_wave_kernel<HIDC><<<GW_BLOCKS, 64, 0, stream>>>(hbuf, W2, dinv, tbuf);
  gather_kernel<<<gGather, B, 0, stream>>>(tbuf, dinv, cnt, csr_pad, b2, hbuf);
  // layer 3
  gemm_wave_kernel<HIDC><<<GW_BLOCKS, 64, 0, stream>>>(hbuf, W3, dinv, tbuf);
  gather_kernel<<<gGather, B, 0, stream>>>(tbuf, dinv, cnt, csr_pad, b3, hbuf);

  // fused readout
  readout_kernel<<<N_GRAPHSC, B, 0, stream>>>(hbuf, closeness, Wc, bc, gstart,
                                              Wa1, ba1, Wa2, ba2, out);
}

// Round 5
// 521.825 us; speedup vs baseline: 1.2606x; 1.2606x over previous
//
#include <hip/hip_runtime.h>

#define N_NODESC 100000
#define N_EDGESC 1600000
#define IN_DIMC 128
#define HIDC 64
#define N_GRAPHSC 512
#define PAD_DEG 64

// ---------------- setup kernels ----------------

// zero 4 cnt replicas + compute per-graph bounds (independent work, one launch)
__global__ void zero_bounds_kernel(int* __restrict__ cntR, const int* __restrict__ batch,
                                   int* __restrict__ gstart) {
  int i = blockIdx.x * blockDim.x + threadIdx.x;
  if (i >= N_NODESC) return;
  cntR[i] = 0;
  cntR[N_NODESC + i] = 0;
  cntR[2 * N_NODESC + i] = 0;
  cntR[3 * N_NODESC + i] = 0;
  int b = batch[i];
  int prev = (i == 0) ? -1 : batch[i - 1];
  for (int g = prev + 1; g <= b; ++g) gstart[g] = i;
  if (i == N_NODESC - 1)
    for (int g = b + 1; g <= N_GRAPHSC; ++g) gstart[g] = N_NODESC;
}

// degree count into 4 replicas (cuts per-line RMW serialization 4x).
// KEEP SPLIT from fill: R1 measured fusing atomic+scattered-store into one
// kernel = 150us vs 65+50 split (both streams share the memory-side
// atomic/write path; dependency adds stalls).
__global__ void deg_kernel(const int* __restrict__ dstv, int* __restrict__ cntR,
                           int* __restrict__ slot) {
  int e4 = (blockIdx.x * blockDim.x + threadIdx.x) * 4;
  if (e4 >= N_EDGESC) return;
  int4 d = *(const int4*)(dstv + e4);
  int4 s;
  s.x = atomicAdd(&cntR[d.x], 1);
  s.y = atomicAdd(&cntR[N_NODESC + d.y], 1);
  s.z = atomicAdd(&cntR[2 * N_NODESC + d.z], 1);
  s.w = atomicAdd(&cntR[3 * N_NODESC + d.w], 1);
  *(int4*)(slot + e4) = s;
}

// per-node: exclusive prefix over replicas -> offR, total cnt, dinv
__global__ void off_dinv_kernel(const int* __restrict__ cntR, int* __restrict__ offR,
                                int* __restrict__ cnt, float* __restrict__ dinv) {
  int i = blockIdx.x * blockDim.x + threadIdx.x;
  if (i >= N_NODESC) return;
  int c0 = cntR[i];
  int c1 = cntR[N_NODESC + i];
  int c2 = cntR[2 * N_NODESC + i];
  int c3 = cntR[3 * N_NODESC + i];
  offR[i] = c0;
  offR[N_NODESC + i] = c0 + c1;
  offR[2 * N_NODESC + i] = c0 + c1 + c2;
  int tot = c0 + c1 + c2 + c3;
  cnt[i] = tot;
  dinv[i] = rsqrtf((float)tot + 1.0f);
}

// atomic-free padded placement: csr_pad[d*64 + offR[r][d] + slot_r[e]] = src
__global__ void fill_pad_kernel(const int* __restrict__ srcv, const int* __restrict__ dstv,
                                const int* __restrict__ slot, const int* __restrict__ offR,
                                int* __restrict__ csr_pad) {
  int e4 = (blockIdx.x * blockDim.x + threadIdx.x) * 4;
  if (e4 >= N_EDGESC) return;
  int4 s = *(const int4*)(srcv + e4);
  int4 d = *(const int4*)(dstv + e4);
  int4 sl = *(const int4*)(slot + e4);
  int p0 = sl.x;
  int p1 = offR[d.y] + sl.y;
  int p2 = offR[N_NODESC + d.z] + sl.z;
  int p3 = offR[2 * N_NODESC + d.w] + sl.w;
  if (p0 < PAD_DEG) __builtin_nontemporal_store(s.x, &csr_pad[d.x * PAD_DEG + p0]);
  if (p1 < PAD_DEG) __builtin_nontemporal_store(s.y, &csr_pad[d.y * PAD_DEG + p1]);
  if (p2 < PAD_DEG) __builtin_nontemporal_store(s.z, &csr_pad[d.z * PAD_DEG + p2]);
  if (p3 < PAD_DEG) __builtin_nontemporal_store(s.w, &csr_pad[d.w * PAD_DEG + p3]);
}

// ---------------- GCN layer GEMM ----------------
// T[tile] = (X[tile] @ W) * dinv.  R0 skeleton (782 blocks = 3.05/CU,
// multi-wave blocks, 12 waves/CU) with an 8x8 per-thread tile:
//  - 128 threads (2 waves), block tile 128 rows x 64 cols, KC=32.
//  - per k: 4 ds_read_b128 per 64 FMA-instr -> per-CU LDS demand (12w x
//    ~32cyc) == SIMD time (12x128/4) -- balanced, vs R0's 3 reads/32 FMA
//    (2x LDS-oversubscribed) and R2-R4's occupancy failures.
//  - staging uses 4-row-packed ds_write_b128 (not 64 scalar writes).
//  - XS_LD=136: staged-write classes (2i+rg)%8 and compute-read classes
//    2(k+g)%8 are both <=2-way aliased (2-way is free, m136).
//  - launch_bounds(128,3): 3 waves/SIMD target, VGPR cap 170 (est ~130);
//    LDS 25.4KB -> 6 blocks/CU = 12 waves/CU.
#define G5_KC 32
#define G5_LD 136
#define G5_BLOCKS ((N_NODESC + 127) / 128)  // 782

template <int KT>
__global__ void __launch_bounds__(128, 3)
gemm8x8_kernel(const float* __restrict__ X, const float* __restrict__ W,
               const float* __restrict__ dinv, float* __restrict__ T) {
  __shared__ float xs[G5_KC * G5_LD];   // xs[k][row] transposed
  __shared__ float ws[G5_KC * 64];      // ws[k][col]
  int t = threadIdx.x;
  int base = blockIdx.x * 128;
  int r0 = (t >> 3) * 8;   // 16 row-groups
  int c0 = (t & 7) * 8;    // 8 col-groups
  int rg = t >> 2;         // staging: row-group of 4 (0..31)
  int kq2 = t & 3;         // staging: k-quad pair selector

  float4 acc[8][2];
#pragma unroll
  for (int i = 0; i < 8; ++i) {
    acc[i][0] = make_float4(0.f, 0.f, 0.f, 0.f);
    acc[i][1] = make_float4(0.f, 0.f, 0.f, 0.f);
  }

  for (int kb = 0; kb < KT; kb += G5_KC) {
    if (kb) __syncthreads();
    // ---- stage X tile (128 rows x 32 k) transposed, b128-packed ----
    // assignment (rg, kq): load 4 rows' float4 at k-quad kq, repack by k,
    // write 4 ds_write_b128 at xs[kq*4+c][rg*4].
#pragma unroll
    for (int a = 0; a < 2; ++a) {
      int kq = kq2 * 2 + a;  // 0..7
      float4 vr[4];
#pragma unroll
      for (int i = 0; i < 4; ++i) {
        int row = base + rg * 4 + i;
        if (row >= N_NODESC) row = N_NODESC - 1;
        vr[i] = *(const float4*)(X + (size_t)row * KT + kb + kq * 4);
      }
      const float* a0 = (const float*)&vr[0];
      const float* a1 = (const float*)&vr[1];
      const float* a2 = (const float*)&vr[2];
      const float* a3 = (const float*)&vr[3];
#pragma unroll
      for (int c = 0; c < 4; ++c) {
        float4 wv = make_float4(a0[c], a1[c], a2[c], a3[c]);
        *(float4*)(xs + (kq * 4 + c) * G5_LD + rg * 4) = wv;
      }
    }
    // ---- stage W chunk (32 k x 64 cols): f = j*128 + t -> 16B/lane coalesced
#pragma unroll
    for (int j = 0; j < 4; ++j) {
      int f = j * 128 + t;
      int kl = f >> 4;
      int c4 = (f & 15) * 4;
      *(float4*)(ws + kl * 64 + c4) = *(const float4*)(W + (size_t)(kb + kl) * HIDC + c4);
    }
    __syncthreads();
    // ---- compute 32 k-steps: 4 b128 reads + 64 FMA per k ----
#pragma unroll 8
    for (int k = 0; k < G5_KC; ++k) {
      float4 xa = *(const float4*)(xs + k * G5_LD + r0);
      float4 xb = *(const float4*)(xs + k * G5_LD + r0 + 4);
      float4 w0 = *(const float4*)(ws + k * 64 + c0);
      float4 w1 = *(const float4*)(ws + k * 64 + c0 + 4);
      float xf[8] = {xa.x, xa.y, xa.z, xa.w, xb.x, xb.y, xb.z, xb.w};
#pragma unroll
      for (int i = 0; i < 8; ++i) {
        acc[i][0].x = fmaf(xf[i], w0.x, acc[i][0].x);
        acc[i][0].y = fmaf(xf[i], w0.y, acc[i][0].y);
        acc[i][0].z = fmaf(xf[i], w0.z, acc[i][0].z);
        acc[i][0].w = fmaf(xf[i], w0.w, acc[i][0].w);
        acc[i][1].x = fmaf(xf[i], w1.x, acc[i][1].x);
        acc[i][1].y = fmaf(xf[i], w1.y, acc[i][1].y);
        acc[i][1].z = fmaf(xf[i], w1.z, acc[i][1].z);
        acc[i][1].w = fmaf(xf[i], w1.w, acc[i][1].w);
      }
    }
  }
  // ---- epilogue: x dinv, store 8 rows x 8 cols ----
#pragma unroll
  for (int i = 0; i < 8; ++i) {
    int row = base + r0 + i;
    if (row < N_NODESC) {
      float dv = dinv[row];
#pragma unroll
      for (int j = 0; j < 2; ++j) {
        float4 o;
        o.x = acc[i][j].x * dv;
        o.y = acc[i][j].y * dv;
        o.z = acc[i][j].z * dv;
        o.w = acc[i][j].w * dv;
        *(float4*)(T + (size_t)row * HIDC + c0 + 4 * j) = o;
      }
    }
  }
}

// h[i][:] = relu(dinv[i]*(ts[i][:] + sum_{s in pad-row i} ts[s][:]) + b)
// Wave layout: lane l = (quarter q=l>>4, col-quad c=l&15). One float4 LOAD
// INSTRUCTION fetches 4 source rows (16B/lane, 1KB/instr). Quarter partials
// folded with shfl_xor(16/32) once per node.
__global__ void gather_kernel(const float* __restrict__ ts, const float* __restrict__ dinv,
                              const int* __restrict__ cnt, const int* __restrict__ csr_pad,
                              const float* __restrict__ bias, float* __restrict__ h) {
  int lane = threadIdx.x & 63;
  int node = (blockIdx.x * blockDim.x + threadIdx.x) >> 6;
  if (node >= N_NODESC) return;
  int q = lane >> 4;        // quarter: which of 4 concurrent edges
  int c = lane & 15;        // col-quad: features 4c..4c+3
  int deg = min(cnt[node], PAD_DEG);
  const int* __restrict__ row = csr_pad + node * PAD_DEG;
  const float4* __restrict__ ts4 = (const float4*)ts;
  float4 acc = make_float4(0.f, 0.f, 0.f, 0.f);
  int e = 0;
  // 16 edges per block: 4 idx loads + 4 float4 loads (16KB in flight across unroll)
  for (; e + 16 <= deg; e += 16) {
    int s0 = row[e + q];
    int s1 = row[e + 4 + q];
    int s2 = row[e + 8 + q];
    int s3 = row[e + 12 + q];
    float4 v0 = ts4[s0 * 16 + c];
    float4 v1 = ts4[s1 * 16 + c];
    float4 v2 = ts4[s2 * 16 + c];
    float4 v3 = ts4[s3 * 16 + c];
    acc.x += (v0.x + v1.x) + (v2.x + v3.x);
    acc.y += (v0.y + v1.y) + (v2.y + v3.y);
    acc.z += (v0.z + v1.z) + (v2.z + v3.z);
    acc.w += (v0.w + v1.w) + (v2.w + v3.w);
  }
  for (; e + 4 <= deg; e += 4) {
    int s0 = row[e + q];
    float4 v = ts4[s0 * 16 + c];
    acc.x += v.x;
    acc.y += v.y;
    acc.z += v.z;
    acc.w += v.w;
  }
  if (e < deg && q < deg - e) {  // tail 1..3 edges, quarters 0..r-1 active
    int s0 = row[e + q];
    float4 v = ts4[s0 * 16 + c];
    acc.x += v.x;
    acc.y += v.y;
    acc.z += v.z;
    acc.w += v.w;
  }
  // fold quarters: lanes ^16 then ^32
  acc.x += __shfl_xor(acc.x, 16);
  acc.y += __shfl_xor(acc.y, 16);
  acc.z += __shfl_xor(acc.z, 16);
  acc.w += __shfl_xor(acc.w, 16);
  acc.x += __shfl_xor(acc.x, 32);
  acc.y += __shfl_xor(acc.y, 32);
  acc.z += __shfl_xor(acc.z, 32);
  acc.w += __shfl_xor(acc.w, 32);
  if (q == 0) {
    float4 self = ts4[node * 16 + c];
    float4 bv = ((const float4*)bias)[c];
    float dv = dinv[node];
    float4 o;
    o.x = fmaxf(fmaf(acc.x + self.x, dv, bv.x), 0.f);
    o.y = fmaxf(fmaf(acc.y + self.y, dv, bv.y), 0.f);
    o.z = fmaxf(fmaf(acc.z + self.z, dv, bv.z), 0.f);
    o.w = fmaxf(fmaf(acc.w + self.w, dv, bv.w), 0.f);
    ((float4*)h)[node * 16 + c] = o;
  }
}

// ---------------- fused readout: score + softmax + weighted max-pool + MLP ----------------
__global__ void __launch_bounds__(256)
readout_kernel(const float* __restrict__ h, const float* __restrict__ closeness,
               const float* __restrict__ Wc, const float* __restrict__ bc,
               const int* __restrict__ gstart, const float* __restrict__ Wa1,
               const float* __restrict__ ba1, const float* __restrict__ Wa2,
               const float* __restrict__ ba2, float* __restrict__ out) {
  __shared__ float sArr[1024];
  __shared__ float red[256];
  __shared__ float cross[4 * 64];
  int g = blockIdx.x;
  int t = threadIdx.x;
  int n0 = gstart[g], n1 = gstart[g + 1];
  int count = n1 - n0;
  int cap = min(count, 1024);
  float wc0 = Wc[0], wc1 = Wc[1], wc2 = Wc[2], wc3 = Wc[3], wc4 = Wc[4], bcv = bc[0];
  float lmax = -3.4e38f;
  for (int idx = t; idx < cap; idx += 256) {
    const float* c = closeness + (size_t)(n0 + idx) * 5;
    float s = fmaf(c[4], wc4, fmaf(c[3], wc3, fmaf(c[2], wc2, fmaf(c[1], wc1, fmaf(c[0], wc0, bcv)))));
    sArr[idx] = s;
    lmax = fmaxf(lmax, s);
  }
  red[t] = lmax;
  __syncthreads();
  for (int s = 128; s > 0; s >>= 1) {
    if (t < s) red[t] = fmaxf(red[t], red[t + s]);
    __syncthreads();
  }
  float m = red[0];
  __syncthreads();
  float lsum = 0.f;
  for (int idx = t; idx < cap; idx += 256) {
    float e = expf(sArr[idx] - m);
    sArr[idx] = e;
    lsum += e;
  }
  red[t] = lsum;
  __syncthreads();
  for (int s = 128; s > 0; s >>= 1) {
    if (t < s) red[t] += red[t + s];
    __syncthreads();
  }
  float scale = (count > 0) ? ((float)count / red[0]) : 0.f;
  __syncthreads();
  int wv = t >> 6, lane = t & 63;
  float pmax = 0.f;  // values nonneg (relu * positive weight)
  for (int idx = wv; idx < cap; idx += 4) {
    float w = sArr[idx] * scale;
    pmax = fmaxf(pmax, w * h[(size_t)(n0 + idx) * HIDC + lane]);
  }
  cross[wv * 64 + lane] = pmax;
  __syncthreads();
  if (wv == 0) {
    float p = fmaxf(fmaxf(cross[lane], cross[64 + lane]),
                    fmaxf(cross[128 + lane], cross[192 + lane]));
    float o = 0.f;
#pragma unroll
    for (int tt = 0; tt < 16; ++tt) {
      float prod = p * Wa1[lane * 16 + tt];
#pragma unroll
      for (int off = 32; off > 0; off >>= 1) prod += __shfl_xor(prod, off);
      float a = fmaxf(prod + ba1[tt], 0.f);
      o += a * Wa2[tt];
    }
    if (lane == 0) out[g] = o + ba2[0];
  }
}

// ---------------- launch ----------------

extern "C" void kernel_launch(void* const* d_in, const int* in_sizes, int n_in,
                              void* d_out, int out_size, void* d_ws, size_t ws_size,
                              hipStream_t stream) {
  const float* x = (const float*)d_in[0];
  const int* ei = (const int*)d_in[1];
  const float* closeness = (const float*)d_in[2];
  const int* batch = (const int*)d_in[3];
  const float* W1 = (const float*)d_in[5];
  const float* b1 = (const float*)d_in[6];
  const float* W2 = (const float*)d_in[7];
  const float* b2 = (const float*)d_in[8];
  const float* W3 = (const float*)d_in[9];
  const float* b3 = (const float*)d_in[10];
  const float* Wc = (const float*)d_in[11];
  const float* bc = (const float*)d_in[12];
  const float* Wa1 = (const float*)d_in[13];
  const float* ba1 = (const float*)d_in[14];
  const float* Wa2 = (const float*)d_in[15];
  const float* ba2 = (const float*)d_in[16];
  float* out = (float*)d_out;
  const int* srcv = ei;
  const int* dstv = ei + N_EDGESC;

  char* ws = (char*)d_ws;
  size_t off = 0;
  auto alloc = [&](size_t bytes) -> void* {
    void* p = ws + off;
    off = (off + bytes + 255) & ~(size_t)255;
    return p;
  };
  float* tbuf = (float*)alloc(sizeof(float) * N_NODESC * HIDC);   // 25.6 MB
  float* hbuf = (float*)alloc(sizeof(float) * N_NODESC * HIDC);   // 25.6 MB
  int* csr_pad = (int*)alloc(sizeof(int) * N_NODESC * PAD_DEG);   // 25.6 MB
  int* slot = (int*)alloc(sizeof(int) * N_EDGESC);                // 6.4 MB
  int* cntR = (int*)alloc(sizeof(int) * N_NODESC * 4);            // 1.6 MB
  int* offR = (int*)alloc(sizeof(int) * N_NODESC * 3);            // 1.2 MB
  int* cnt = (int*)alloc(sizeof(int) * N_NODESC);
  float* dinv = (float*)alloc(sizeof(float) * N_NODESC);
  int* gstart = (int*)alloc(sizeof(int) * (N_GRAPHSC + 1));

  const int B = 256;
  int gN = (N_NODESC + B - 1) / B;           // 391
  int gE4 = (N_EDGESC / 4 + B - 1) / B;      // 1563
  int gGather = (N_NODESC * 64) / B;         // 25000

  zero_bounds_kernel<<<gN, B, 0, stream>>>(cntR, batch, gstart);
  deg_kernel<<<gE4, B, 0, stream>>>(dstv, cntR, slot);
  off_dinv_kernel<<<gN, B, 0, stream>>>(cntR, offR, cnt, dinv);
  fill_pad_kernel<<<gE4, B, 0, stream>>>(srcv, dstv, slot, offR, csr_pad);

  // layer 1 (K=128)
  gemm8x8_kernel<IN_DIMC><<<G5_BLOCKS, 128, 0, stream>>>(x, W1, dinv, tbuf);
  gather_kernel<<<gGather, B, 0, stream>>>(tbuf, dinv, cnt, csr_pad, b1, hbuf);
  // layer 2
  gemm8x8_kernel<HIDC><<<G5_BLOCKS, 128, 0, stream>>>(hbuf, W2, dinv, tbuf);
  gather_kernel<<<gGather, B, 0, stream>>>(tbuf, dinv, cnt, csr_pad, b2, hbuf);
  // layer 3
  gemm8x8_kernel<HIDC><<<G5_BLOCKS, 128, 0, stream>>>(hbuf, W3, dinv, tbuf);
  gather_kernel<<<gGather, B, 0, stream>>>(tbuf, dinv, cnt, csr_pad, b3, hbuf);

  // fused readout
  readout_kernel<<<N_GRAPHSC, B, 0, stream>>>(hbuf, closeness, Wc, bc, gstart,
                                              Wa1, ba1, Wa2, ba2, out);
}